// Round 19
// baseline (49.140 us; speedup 1.0000x reference)
//
#include <hip/hip_runtime.h>

// SoftSmoothAP on MI355X. B=384, C=48, D=512. Output: scalar f32 loss = 1 - AP.
//
//   simk = clamp(sim*100*log2e, +-45); E = 2^simk; sg(p,q) = Eq/(Eq+Ep)
//   denom[i,p] = 0.5 + F_i(kp),  F_i(x) = sum_q sigma(kq - x)  [one smooth fn/row]
//   loss = 1 - (1/B) sum_{i,c} sl*w[c] * sum_{p in P_c} (0.5 + sum_{q in P_c} sg)/denom
//
// R19: measurement (R17/R18) pinned: fixed overhead ~15us, simprep ~9, mega ~20
// (issue-roofline ~10cy/wave-sigE). Cut sigmoid COUNT: F evaluated at 128
// uniform nodes (24.6K sigE/block vs 73.7K) + cubic Lagrange interp at each kp
// (err ~1e-3 << 9.8e-3 threshold). Self-p via exact tail 1 + 2^-45*SE_noself.
// Phase B exact (unchanged). 3 kernels: simprep -> nodesF -> phaseC.

#define BB 384
#define CC 48
#define DD 512
#define HALF 192
#define MAXE 3072
#define NNODE 128
#define SCALE 144.269504089f  // 100 * log2(e)

__device__ __forceinline__ float sigE(float Eq, float Ep) {
    return Eq * __builtin_amdgcn_rcpf(Eq + Ep);
}

// ---- 1. sim tiles (blocks 0..143 = 36 tiles x 4 k-chunks) + prep (block 144) -
__global__ __launch_bounds__(256) void simprep_kernel(
    const float* __restrict__ preds, const float* __restrict__ softlabels,
    float* __restrict__ simpart, float* __restrict__ wclass,
    int* __restrict__ cls_off, unsigned short* __restrict__ plist,
    int* __restrict__ ent_lo, int* __restrict__ ent_hi, int* __restrict__ nE3,
    float* __restrict__ out) {
    int tid = threadIdx.x;

    if (blockIdx.x < 144) {
        int t = blockIdx.x >> 2, kc = blockIdx.x & 3;
        int bi = t / 6, bj = t % 6;
        __shared__ __align__(16) float s_a[128][68];
        __shared__ __align__(16) float s_b[128][68];
        int kbase = kc * 128;
#pragma unroll
        for (int it = 0; it < 8; ++it) {
            int idx = it * 256 + tid;
            int r = idx >> 5;
            int c4 = idx & 31;
            float4 va = *reinterpret_cast<const float4*>(
                preds + (bi * 64 + r) * DD + kbase + c4 * 4);
            float4 vb = *reinterpret_cast<const float4*>(
                preds + (bj * 64 + r) * DD + kbase + c4 * 4);
            s_a[c4 * 4 + 0][r] = va.x; s_a[c4 * 4 + 1][r] = va.y;
            s_a[c4 * 4 + 2][r] = va.z; s_a[c4 * 4 + 3][r] = va.w;
            s_b[c4 * 4 + 0][r] = vb.x; s_b[c4 * 4 + 1][r] = vb.y;
            s_b[c4 * 4 + 2][r] = vb.z; s_b[c4 * 4 + 3][r] = vb.w;
        }
        __syncthreads();
        int ty = tid >> 4, tx = tid & 15;
        float4 acc0 = {0,0,0,0}, acc1 = {0,0,0,0}, acc2 = {0,0,0,0}, acc3 = {0,0,0,0};
#pragma unroll 4
        for (int k = 0; k < 128; ++k) {
            float4 a4 = *reinterpret_cast<const float4*>(&s_a[k][ty * 4]);
            float4 b4 = *reinterpret_cast<const float4*>(&s_b[k][tx * 4]);
            acc0.x += a4.x * b4.x; acc0.y += a4.x * b4.y; acc0.z += a4.x * b4.z; acc0.w += a4.x * b4.w;
            acc1.x += a4.y * b4.x; acc1.y += a4.y * b4.y; acc1.z += a4.y * b4.z; acc1.w += a4.y * b4.w;
            acc2.x += a4.z * b4.x; acc2.y += a4.z * b4.y; acc2.z += a4.z * b4.z; acc2.w += a4.z * b4.w;
            acc3.x += a4.w * b4.x; acc3.y += a4.w * b4.y; acc3.z += a4.w * b4.z; acc3.w += a4.w * b4.w;
        }
        float* dst = simpart + kc * (BB * BB) + (bi * 64 + ty * 4) * BB + bj * 64 + tx * 4;
        *reinterpret_cast<float4*>(dst + 0 * BB) = acc0;
        *reinterpret_cast<float4*>(dst + 1 * BB) = acc1;
        *reinterpret_cast<float4*>(dst + 2 * BB) = acc2;
        *reinterpret_cast<float4*>(dst + 3 * BB) = acc3;
    } else {
        __shared__ unsigned int s_mlo[BB];
        __shared__ unsigned int s_mhi[BB];
        __shared__ int s_cnt[CC];
        __shared__ int s_lcnt[CC];
        __shared__ int s_soff[CC + 1];
        __shared__ int s_loff[CC + 1];
        __shared__ int s_hoff[CC + 1];
        int wave = tid >> 6, lane = tid & 63;

        for (int p = tid; p < BB; p += 256) {
            const float4* rowp = reinterpret_cast<const float4*>(softlabels + p * CC);
            unsigned int lo = 0, hi = 0;
#pragma unroll
            for (int v = 0; v < 12; ++v) {
                float4 x = rowp[v];
                unsigned int b = (x.x > 0.f ? 1u : 0u) | (x.y > 0.f ? 2u : 0u) |
                                 (x.z > 0.f ? 4u : 0u) | (x.w > 0.f ? 8u : 0u);
                if (v < 8) lo |= b << (4 * v);
                else       hi |= b << (4 * (v - 8));
            }
            s_mlo[p] = lo;
            s_mhi[p] = hi;
        }
        __syncthreads();

        for (int c = wave; c < CC; c += 4) {
            int cnt = 0, lcnt = 0;
#pragma unroll
            for (int t = 0; t < BB / 64; ++t) {
                int p = t * 64 + lane;
                bool pos = ((c < 32 ? (s_mlo[p] >> c) : (s_mhi[p] >> (c - 32))) & 1u) != 0u;
                int n = __popcll(__ballot(pos));
                cnt += n;
                if (t < 3) lcnt += n;
            }
            if (lane == 0) {
                s_cnt[c] = cnt;
                s_lcnt[c] = lcnt;
                wclass[c] = (cnt >= 4) ? (1.0f / (float)cnt) : 0.0f;
            }
        }
        __syncthreads();
        if (tid < 64) {
            int a = (tid < CC) ? s_cnt[tid] : 0;
            int l = (tid < CC) ? s_lcnt[tid] : 0;
            int hg = a - l;
#pragma unroll
            for (int d = 1; d < 64; d <<= 1) {
                int oa = __shfl_up(a, d, 64);
                int ol = __shfl_up(l, d, 64);
                int oh = __shfl_up(hg, d, 64);
                if (tid >= d) { a += oa; l += ol; hg += oh; }
            }
            if (tid < CC) { s_soff[tid + 1] = a; s_loff[tid + 1] = l; s_hoff[tid + 1] = hg; }
            if (tid == 0) { s_soff[0] = 0; s_loff[0] = 0; s_hoff[0] = 0; }
            if (tid == CC - 1) { nE3[0] = a; nE3[1] = l; nE3[2] = hg; }
        }
        __syncthreads();
        if (tid <= CC) cls_off[tid] = s_soff[tid];
        for (int c = wave; c < CC; c += 4) {
            int base = 0;
            int off = s_soff[c], L = s_lcnt[c], lo = s_loff[c], ho = s_hoff[c];
#pragma unroll
            for (int t = 0; t < BB / 64; ++t) {
                int p = t * 64 + lane;
                bool pos = ((c < 32 ? (s_mlo[p] >> c) : (s_mhi[p] >> (c - 32))) & 1u) != 0u;
                unsigned long long m = __ballot(pos);
                if (pos) {
                    int idx = base + __popcll(m & ((1ull << lane) - 1ull));
                    plist[off + idx] = (unsigned short)p;
                    int pk = (c << 16) | p;
                    if (idx < L) ent_lo[lo + idx] = pk;
                    else         ent_hi[ho + idx - L] = pk;
                }
                base += __popcll(m);
            }
        }
        if (tid == 0) out[0] = 1.0f;
    }
}

// ---- 2. nodesF: block (i,h) -> F at 128 nodes over own-half q ----------------
__global__ __launch_bounds__(512) void nodesF_kernel(
    const float* __restrict__ simpart, float* __restrict__ Erow,
    float* __restrict__ skrow, float* __restrict__ rowmeta,
    float* __restrict__ Fpart, float* __restrict__ SEpart) {
    int i = blockIdx.x >> 1, h = blockIdx.x & 1;
    int tid = threadIdx.x;
    int wave = tid >> 6, lane = tid & 63;
    __shared__ float s_sk[BB];
    __shared__ __align__(16) float s_E[BB];
    __shared__ float s_mm[16];
    __shared__ float s_Fp[4][NNODE];
    __shared__ float s_se[8];

    if (tid < BB) {
        int x = i * BB + tid;
        float sim = (simpart[x] + simpart[BB * BB + x]) +
                    (simpart[2 * BB * BB + x] + simpart[3 * BB * BB + x]);
        s_sk[tid] = fminf(fmaxf(sim * SCALE, -45.0f), 45.0f);
    }
    __syncthreads();
    // row min (all) / max (excluding self)
    float mx = -1e30f, mn = 1e30f;
    if (tid < BB) {
        float v = s_sk[tid];
        mn = v;
        mx = (tid == i) ? -1e30f : v;
    }
#pragma unroll
    for (int off = 32; off > 0; off >>= 1) {
        mx = fmaxf(mx, __shfl_xor(mx, off, 64));
        mn = fminf(mn, __shfl_xor(mn, off, 64));
    }
    if (lane == 0) { s_mm[wave] = mx; s_mm[8 + wave] = mn; }
    __syncthreads();
    mx = s_mm[0]; mn = s_mm[8];
#pragma unroll
    for (int w = 1; w < 8; ++w) { mx = fmaxf(mx, s_mm[w]); mn = fminf(mn, s_mm[8 + w]); }
    float lo = mn - 0.5f, hi = mx + 0.5f;
    float rng = fmaxf(hi - lo, 1e-3f);
    float step = rng * (1.0f / (NNODE - 1));
    float invh = (NNODE - 1) / rng;

    if (tid < HALF) {
        int q = h * HALF + tid;
        float e = __builtin_amdgcn_exp2f(s_sk[q]);
        s_E[q] = e;
        Erow[i * BB + q] = e;
        skrow[i * BB + q] = s_sk[q];
    }
    if (h == 0 && tid == 0) {
        rowmeta[i * 4 + 0] = lo;
        rowmeta[i * 4 + 1] = invh;
    }
    __syncthreads();

    // F-scan: thread = (node n, q-chunk); En per lane, q reads wave-uniform bcast
    {
        int n = tid & (NNODE - 1);
        int chunk = tid >> 7;  // 0..3, wave-uniform
        float En = __builtin_amdgcn_exp2f(lo + (float)n * step);
        const float4* sv = reinterpret_cast<const float4*>(s_E + h * HALF + chunk * 48);
        float a0 = 0.f, a1 = 0.f, a2 = 0.f, a3 = 0.f;
#pragma unroll
        for (int t = 0; t < 12; ++t) {
            float4 v = sv[t];
            a0 += sigE(v.x, En);
            a1 += sigE(v.y, En);
            a2 += sigE(v.z, En);
            a3 += sigE(v.w, En);
        }
        s_Fp[chunk][n] = (a0 + a1) + (a2 + a3);
    }
    // SE (own half, excluding self)
    float se = 0.f;
    if (tid < HALF) {
        int q = h * HALF + tid;
        se = (q == i) ? 0.f : s_E[q];
    }
#pragma unroll
    for (int off = 32; off > 0; off >>= 1) se += __shfl_down(se, off, 64);
    if (lane == 0) s_se[wave] = se;
    __syncthreads();
    if (tid < NNODE)
        Fpart[(i * 2 + h) * NNODE + tid] =
            (s_Fp[0][tid] + s_Fp[1][tid]) + (s_Fp[2][tid] + s_Fp[3][tid]);
    if (tid == 0) {
        float t = 0.f;
#pragma unroll
        for (int w = 0; w < 8; ++w) t += s_se[w];
        SEpart[i * 2 + h] = t;
    }
}

// ---- 3. phaseC: spline denominators + exact phase B --------------------------
__global__ __launch_bounds__(576) void phaseC_kernel(
    const float* __restrict__ Erow, const float* __restrict__ skrow,
    const float* __restrict__ rowmeta, const float* __restrict__ Fpart,
    const float* __restrict__ SEpart, const float* __restrict__ softlabels,
    const float* __restrict__ wclass, const int* __restrict__ cls_off,
    const unsigned short* __restrict__ plist, const int* __restrict__ ent_lo,
    const int* __restrict__ ent_hi, const int* __restrict__ nE3,
    float* __restrict__ out) {
    int i = blockIdx.x >> 1, h = blockIdx.x & 1;
    int tid = threadIdx.x;
    int wave = tid >> 6, lane = tid & 63;

    __shared__ __align__(16) float s_E[BB];
    __shared__ float s_F[NNODE];
    __shared__ float s_inv[HALF];
    __shared__ float s_wsl[CC];
    __shared__ int s_off[CC + 1];
    __shared__ float s_Eq[MAXE];
    __shared__ float s_red[9];

    if (tid < BB) s_E[tid] = Erow[i * BB + tid];
    if (tid < NNODE)
        s_F[tid] = Fpart[(i * 2) * NNODE + tid] + Fpart[(i * 2 + 1) * NNODE + tid];
    if (tid < CC) s_wsl[tid] = wclass[tid] * softlabels[i * CC + tid];
    if (tid <= CC) s_off[tid] = cls_off[tid];
    __syncthreads();
    int nE = s_off[CC];
    for (int e = tid; e < nE; e += 576) s_Eq[e] = s_E[plist[e]];

    // denominators: cubic Lagrange on F nodes; self-p via exact tail
    if (tid < HALF) {
        int p = h * HALF + tid;
        float d;
        if (p == i) {
            float SE = SEpart[i * 2] + SEpart[i * 2 + 1];
            d = 1.0f + SE * 2.84217094e-14f;  // 2^-45
        } else {
            float lo = rowmeta[i * 4 + 0], invh = rowmeta[i * 4 + 1];
            float t = (skrow[i * BB + p] - lo) * invh;
            int j = (int)floorf(t);
            j = min(max(j, 1), NNODE - 3);
            float u = t - (float)j;
            float f0 = s_F[j - 1], f1 = s_F[j], f2 = s_F[j + 1], f3 = s_F[j + 2];
            float um1 = u + 1.f, u1 = u - 1.f, u2 = u - 2.f;
            float c0 = -u * u1 * u2 * (1.f / 6.f);
            float c1 = um1 * u1 * u2 * (1.f / 2.f);
            float c2 = -um1 * u * u2 * (1.f / 2.f);
            float c3 = um1 * u * u1 * (1.f / 6.f);
            d = 0.5f + (c0 * f0 + c1 * f1) + (c2 * f2 + c3 * f3);
        }
        s_inv[tid] = __builtin_amdgcn_rcpf(d);
    }
    __syncthreads();

    // phase B: exact, entry-parallel over own half's entries
    const int* ent = h ? ent_hi : ent_lo;
    int n = nE3[1 + h];
    float part = 0.f;
    for (int e = tid; e < n; e += 576) {
        int pk = ent[e];
        int c = pk >> 16, p = pk & 0xFFFF;
        int off = s_off[c], m = s_off[c + 1] - off;
        float Ep = s_E[p];
        float b0 = 0.f, b1 = 0.f, b2 = 0.f, b3 = 0.f;
        int j = 0;
        for (; j + 3 < m; j += 4) {
            b0 += sigE(s_Eq[off + j], Ep);
            b1 += sigE(s_Eq[off + j + 1], Ep);
            b2 += sigE(s_Eq[off + j + 2], Ep);
            b3 += sigE(s_Eq[off + j + 3], Ep);
        }
        for (; j < m; ++j) b0 += sigE(s_Eq[off + j], Ep);
        float s = (b0 + b1) + (b2 + b3);
        part += (0.5f + s) * s_inv[p - h * HALF] * s_wsl[c];
    }

    for (int off = 32; off > 0; off >>= 1) part += __shfl_down(part, off, 64);
    if (lane == 0) s_red[wave] = part;
    __syncthreads();
    if (tid == 0) {
        float tot = 0.f;
#pragma unroll
        for (int w = 0; w < 9; ++w) tot += s_red[w];
        atomicAdd(out, -tot * (1.0f / (float)BB));
    }
}

extern "C" void kernel_launch(void* const* d_in, const int* in_sizes, int n_in,
                              void* d_out, int out_size, void* d_ws, size_t ws_size,
                              hipStream_t stream) {
    const float* preds = (const float*)d_in[0];       // (384,512) f32
    const float* softlabels = (const float*)d_in[1];  // (384,48) f32
    float* out = (float*)d_out;

    char* ws = (char*)d_ws;
    float*          simpart = (float*)(ws + 0);        // 2359296
    float*          wclass  = (float*)(ws + 2359296);  // 192
    int*            cls_off = (int*)(ws + 2359488);    // 256
    unsigned short* plist   = (unsigned short*)(ws + 2359744);  // 6144
    int*            ent_lo  = (int*)(ws + 2365888);    // 12288
    int*            ent_hi  = (int*)(ws + 2378176);    // 12288
    int*            nE3     = (int*)(ws + 2390464);    // 64 (pad)
    float*          Erow    = (float*)(ws + 2390528);  // 589824
    float*          skrow   = (float*)(ws + 2980352);  // 589824
    float*          Fpart   = (float*)(ws + 3570176);  // 393216
    float*          SEpart  = (float*)(ws + 3963392);  // 3072
    float*          rowmeta = (float*)(ws + 3966464);  // 6144 -> 3972608 total

    simprep_kernel<<<145, 256, 0, stream>>>(preds, softlabels, simpart, wclass,
                                            cls_off, plist, ent_lo, ent_hi, nE3, out);
    nodesF_kernel<<<BB * 2, 512, 0, stream>>>(simpart, Erow, skrow, rowmeta,
                                              Fpart, SEpart);
    phaseC_kernel<<<BB * 2, 576, 0, stream>>>(Erow, skrow, rowmeta, Fpart, SEpart,
                                              softlabels, wclass, cls_off, plist,
                                              ent_lo, ent_hi, nE3, out);
}

// Round 20
// 37.513 us; speedup vs baseline: 1.3099x; 1.3099x over previous
//
#include <hip/hip_runtime.h>

// SoftSmoothAP on MI355X. B=384, C=48, D=512. Output: scalar f32 loss = 1 - AP.
//
//   simk = clamp(sim*100*log2e, +-45); E = 2^simk; sg(p,q) = Eq/(Eq+Ep)
//   denom[i,p] = 0.5 + F_i(kp),  F_i(x) = sum_q sigma(kq - x)
//   F_i computed at 128 uniform nodes IN-BLOCK, cubic-Lagrange interp at each kp
//   (R19 validated spline accuracy: absmax 0.0). Self-p exact: 1 + 2^-45*SE.
//   loss = 1 - (1/B) sum_{i,c} sl*w[c] * sum_{p in P_c} (0.5 + sum_{q in P_c} sg)/denom
//
// R20: R19's spline fused into ONE row-per-block kernel (grid 384 x 1024 thr)
// -- no third kernel, no Erow/skrow/Fpart global round-trips (that cost +5us).
// Row work: 217K -> 119K sigE. simprep = R13 GEMM + simplified prep (flat only).

#define BB 384
#define CC 48
#define DD 512
#define MAXE 3072
#define NNODE 128
#define SCALE 144.269504089f  // 100 * log2(e)

__device__ __forceinline__ float sigE(float Eq, float Ep) {
    return Eq * __builtin_amdgcn_rcpf(Eq + Ep);
}

// ---- 1. sim tiles (blocks 0..143 = 36 tiles x 4 k-chunks) + prep (block 144) -
__global__ __launch_bounds__(256) void simprep_kernel(
    const float* __restrict__ preds, const float* __restrict__ softlabels,
    float* __restrict__ simpart, float* __restrict__ wclass,
    int* __restrict__ cls_off, int* __restrict__ flat_pack,
    int* __restrict__ nE_p, float* __restrict__ out) {
    int tid = threadIdx.x;

    if (blockIdx.x < 144) {
        int t = blockIdx.x >> 2, kc = blockIdx.x & 3;
        int bi = t / 6, bj = t % 6;
        __shared__ __align__(16) float s_a[128][68];
        __shared__ __align__(16) float s_b[128][68];
        int kbase = kc * 128;
#pragma unroll
        for (int it = 0; it < 8; ++it) {
            int idx = it * 256 + tid;
            int r = idx >> 5;
            int c4 = idx & 31;
            float4 va = *reinterpret_cast<const float4*>(
                preds + (bi * 64 + r) * DD + kbase + c4 * 4);
            float4 vb = *reinterpret_cast<const float4*>(
                preds + (bj * 64 + r) * DD + kbase + c4 * 4);
            s_a[c4 * 4 + 0][r] = va.x; s_a[c4 * 4 + 1][r] = va.y;
            s_a[c4 * 4 + 2][r] = va.z; s_a[c4 * 4 + 3][r] = va.w;
            s_b[c4 * 4 + 0][r] = vb.x; s_b[c4 * 4 + 1][r] = vb.y;
            s_b[c4 * 4 + 2][r] = vb.z; s_b[c4 * 4 + 3][r] = vb.w;
        }
        __syncthreads();
        int ty = tid >> 4, tx = tid & 15;
        float4 acc0 = {0,0,0,0}, acc1 = {0,0,0,0}, acc2 = {0,0,0,0}, acc3 = {0,0,0,0};
#pragma unroll 4
        for (int k = 0; k < 128; ++k) {
            float4 a4 = *reinterpret_cast<const float4*>(&s_a[k][ty * 4]);
            float4 b4 = *reinterpret_cast<const float4*>(&s_b[k][tx * 4]);
            acc0.x += a4.x * b4.x; acc0.y += a4.x * b4.y; acc0.z += a4.x * b4.z; acc0.w += a4.x * b4.w;
            acc1.x += a4.y * b4.x; acc1.y += a4.y * b4.y; acc1.z += a4.y * b4.z; acc1.w += a4.y * b4.w;
            acc2.x += a4.z * b4.x; acc2.y += a4.z * b4.y; acc2.z += a4.z * b4.z; acc2.w += a4.z * b4.w;
            acc3.x += a4.w * b4.x; acc3.y += a4.w * b4.y; acc3.z += a4.w * b4.z; acc3.w += a4.w * b4.w;
        }
        float* dst = simpart + kc * (BB * BB) + (bi * 64 + ty * 4) * BB + bj * 64 + tx * 4;
        *reinterpret_cast<float4*>(dst + 0 * BB) = acc0;
        *reinterpret_cast<float4*>(dst + 1 * BB) = acc1;
        *reinterpret_cast<float4*>(dst + 2 * BB) = acc2;
        *reinterpret_cast<float4*>(dst + 3 * BB) = acc3;
    } else {
        // ---- prep: masks -> counts -> scan -> flat (c,p) list ----
        __shared__ unsigned int s_mlo[BB];
        __shared__ unsigned int s_mhi[BB];
        __shared__ int s_cnt[CC];
        __shared__ int s_soff[CC + 1];
        int wave = tid >> 6, lane = tid & 63;

        for (int p = tid; p < BB; p += 256) {
            const float4* rowp = reinterpret_cast<const float4*>(softlabels + p * CC);
            unsigned int lo = 0, hi = 0;
#pragma unroll
            for (int v = 0; v < 12; ++v) {
                float4 x = rowp[v];
                unsigned int b = (x.x > 0.f ? 1u : 0u) | (x.y > 0.f ? 2u : 0u) |
                                 (x.z > 0.f ? 4u : 0u) | (x.w > 0.f ? 8u : 0u);
                if (v < 8) lo |= b << (4 * v);
                else       hi |= b << (4 * (v - 8));
            }
            s_mlo[p] = lo;
            s_mhi[p] = hi;
        }
        __syncthreads();

        for (int c = wave; c < CC; c += 4) {
            int cnt = 0;
#pragma unroll
            for (int t = 0; t < BB / 64; ++t) {
                int p = t * 64 + lane;
                bool pos = ((c < 32 ? (s_mlo[p] >> c) : (s_mhi[p] >> (c - 32))) & 1u) != 0u;
                cnt += __popcll(__ballot(pos));
            }
            if (lane == 0) {
                s_cnt[c] = cnt;
                wclass[c] = (cnt >= 4) ? (1.0f / (float)cnt) : 0.0f;
            }
        }
        __syncthreads();
        if (tid < 64) {
            int v = (tid < CC) ? s_cnt[tid] : 0;
#pragma unroll
            for (int d = 1; d < 64; d <<= 1) {
                int o = __shfl_up(v, d, 64);
                if (tid >= d) v += o;
            }
            if (tid < CC) s_soff[tid + 1] = v;
            if (tid == 0) s_soff[0] = 0;
            if (tid == CC - 1) *nE_p = v;
        }
        __syncthreads();
        if (tid <= CC) cls_off[tid] = s_soff[tid];
        for (int c = wave; c < CC; c += 4) {
            int base = s_soff[c];
#pragma unroll
            for (int t = 0; t < BB / 64; ++t) {
                int p = t * 64 + lane;
                bool pos = ((c < 32 ? (s_mlo[p] >> c) : (s_mhi[p] >> (c - 32))) & 1u) != 0u;
                unsigned long long m = __ballot(pos);
                if (pos)
                    flat_pack[base + __popcll(m & ((1ull << lane) - 1ull))] = (c << 16) | p;
                base += __popcll(m);
            }
        }
        if (tid == 0) out[0] = 1.0f;
    }
}

// ---- 2. megaF: one row per block; in-block node spline + exact phase B -------
__global__ __launch_bounds__(1024) void mega_kernel(
    const float* __restrict__ simpart, const float* __restrict__ softlabels,
    const float* __restrict__ wclass, const int* __restrict__ cls_off,
    const int* __restrict__ flat_pack, const int* __restrict__ nE_p,
    float* __restrict__ out) {
    int i = blockIdx.x;
    int tid = threadIdx.x;
    int wave = tid >> 6, lane = tid & 63;

    __shared__ float s_sk[BB];
    __shared__ __align__(16) float s_E[BB];
    __shared__ float s_F[NNODE];
    __shared__ float s_Fp[8][NNODE];
    __shared__ float s_inv[BB];
    __shared__ float s_wsl[CC];
    __shared__ int s_off[CC + 1];
    __shared__ float s_Eq[MAXE];
    __shared__ float s_red[16];
    __shared__ float s_mx[16], s_mn[16], s_se[16];

    int nE = *nE_p;
    if (tid < BB) {
        int x = i * BB + tid;
        float sim = (simpart[x] + simpart[BB * BB + x]) +
                    (simpart[2 * BB * BB + x] + simpart[3 * BB * BB + x]);
        float sk = fminf(fmaxf(sim * SCALE, -45.0f), 45.0f);  // only self-sim clamps
        s_sk[tid] = sk;
        s_E[tid] = __builtin_amdgcn_exp2f(sk);
    }
    if (tid < CC) s_wsl[tid] = wclass[tid] * softlabels[i * CC + tid];
    if (tid <= CC) s_off[tid] = cls_off[tid];
    __syncthreads();

    // stage per-entry Eq (L2-hot flat_pack)
    for (int e = tid; e < nE; e += 1024) s_Eq[e] = s_E[flat_pack[e] & 0xFFFF];

    // min (all) / max (excl. self) / SE = sum E (excl. self)
    float mx = -1e30f, mn = 1e30f, se = 0.f;
    if (tid < BB) {
        float v = s_sk[tid];
        mn = v;
        if (tid != i) { mx = v; se = s_E[tid]; }
    }
#pragma unroll
    for (int off = 32; off > 0; off >>= 1) {
        mx = fmaxf(mx, __shfl_xor(mx, off, 64));
        mn = fminf(mn, __shfl_xor(mn, off, 64));
        se += __shfl_xor(se, off, 64);
    }
    if (lane == 0) { s_mx[wave] = mx; s_mn[wave] = mn; s_se[wave] = se; }
    __syncthreads();
    mx = s_mx[0]; mn = s_mn[0]; se = s_se[0];
#pragma unroll
    for (int w = 1; w < 16; ++w) {
        mx = fmaxf(mx, s_mx[w]);
        mn = fminf(mn, s_mn[w]);
        se += s_se[w];
    }
    float lo = mn - 0.5f;
    float rng = fmaxf((mx + 0.5f) - lo, 1e-3f);
    float step = rng * (1.0f / (NNODE - 1));
    float invh = (NNODE - 1) / rng;

    // F at 128 nodes: thread = (node, q-chunk of 48); broadcast LDS reads
    {
        int n = tid & (NNODE - 1);
        int chunk = tid >> 7;  // 0..7, wave-uniform
        float En = __builtin_amdgcn_exp2f(lo + (float)n * step);
        const float4* sv = reinterpret_cast<const float4*>(s_E + chunk * 48);
        float a0 = 0.f, a1 = 0.f, a2 = 0.f, a3 = 0.f;
#pragma unroll
        for (int t = 0; t < 12; ++t) {
            float4 v = sv[t];
            a0 += sigE(v.x, En);
            a1 += sigE(v.y, En);
            a2 += sigE(v.z, En);
            a3 += sigE(v.w, En);
        }
        s_Fp[chunk][n] = (a0 + a1) + (a2 + a3);
    }
    __syncthreads();
    if (tid < NNODE) {
        float f = 0.f;
#pragma unroll
        for (int c8 = 0; c8 < 8; ++c8) f += s_Fp[c8][tid];
        s_F[tid] = f;
    }
    __syncthreads();

    // denominators: cubic Lagrange; self-p exact tail
    if (tid < BB) {
        float d;
        if (tid == i) {
            d = 1.0f + se * 2.84217094e-14f;  // 2^-45 * SE
        } else {
            float t = (s_sk[tid] - lo) * invh;
            int j = (int)floorf(t);
            j = min(max(j, 1), NNODE - 3);
            float u = t - (float)j;
            float f0 = s_F[j - 1], f1 = s_F[j], f2 = s_F[j + 1], f3 = s_F[j + 2];
            float um1 = u + 1.f, u1 = u - 1.f, u2 = u - 2.f;
            float c0 = -u * u1 * u2 * (1.f / 6.f);
            float c1 = um1 * u1 * u2 * (1.f / 2.f);
            float c2 = -um1 * u * u2 * (1.f / 2.f);
            float c3 = um1 * u * u1 * (1.f / 6.f);
            d = 0.5f + (c0 * f0 + c1 * f1) + (c2 * f2 + c3 * f3);
        }
        s_inv[tid] = __builtin_amdgcn_rcpf(d);
    }
    __syncthreads();

    // phase B: exact, entry-parallel over full list
    float part = 0.f;
    for (int e = tid; e < nE; e += 1024) {
        int pk = flat_pack[e];
        int c = pk >> 16, p = pk & 0xFFFF;
        int off = s_off[c], m = s_off[c + 1] - off;
        float Ep = s_E[p];
        float b0 = 0.f, b1 = 0.f, b2 = 0.f, b3 = 0.f;
        int j = 0;
        for (; j + 3 < m; j += 4) {
            b0 += sigE(s_Eq[off + j], Ep);
            b1 += sigE(s_Eq[off + j + 1], Ep);
            b2 += sigE(s_Eq[off + j + 2], Ep);
            b3 += sigE(s_Eq[off + j + 3], Ep);
        }
        for (; j < m; ++j) b0 += sigE(s_Eq[off + j], Ep);
        float s = (b0 + b1) + (b2 + b3);
        // s includes q==p (=0.5): numerator = 0.5 + s
        part += (0.5f + s) * s_inv[p] * s_wsl[c];
    }

    for (int off = 32; off > 0; off >>= 1) part += __shfl_down(part, off, 64);
    if (lane == 0) s_red[wave] = part;
    __syncthreads();
    if (tid == 0) {
        float tot = 0.f;
#pragma unroll
        for (int w = 0; w < 16; ++w) tot += s_red[w];
        atomicAdd(out, -tot * (1.0f / (float)BB));
    }
}

extern "C" void kernel_launch(void* const* d_in, const int* in_sizes, int n_in,
                              void* d_out, int out_size, void* d_ws, size_t ws_size,
                              hipStream_t stream) {
    const float* preds = (const float*)d_in[0];       // (384,512) f32
    const float* softlabels = (const float*)d_in[1];  // (384,48) f32
    float* out = (float*)d_out;

    char* ws = (char*)d_ws;
    float* simpart  = (float*)(ws + 0);        // 2359296
    float* wclass   = (float*)(ws + 2359296);  // 192
    int*   cls_off  = (int*)(ws + 2359488);    // 256
    int*   flat_pk  = (int*)(ws + 2359744);    // 12288
    int*   nE_p     = (int*)(ws + 2372032);    // 4

    simprep_kernel<<<145, 256, 0, stream>>>(preds, softlabels, simpart, wclass,
                                            cls_off, flat_pk, nE_p, out);
    mega_kernel<<<BB, 1024, 0, stream>>>(simpart, softlabels, wclass, cls_off,
                                         flat_pk, nE_p, out);
}

// Round 21
// 32.849 us; speedup vs baseline: 1.4959x; 1.1420x over previous
//
#include <hip/hip_runtime.h>

// SoftSmoothAP on MI355X. B=384, C=48, D=512. Output: scalar f32 loss = 1 - AP.
//
//   simk = clamp(sim*100*log2e, +-45); E = 2^simk; sg(p,q) = Eq/(Eq+Ep)
//   denom[i,p] = 0.5 + F_i(kp),  F_i(x) = sum_q sigma(kq - x)
//   F_i at 64 uniform nodes IN-BLOCK (F is ultra-smooth: sum of 384 smeared
//   sigmoids -> cubic interp effectively exact; R19/R20 absmax 0.0), cubic
//   Lagrange at each kp; self-p exact: 1 + 2^-45*SE.
//   loss = 1 - (1/B) sum_{i,c} sl*w[c] * sum_{p in P_c} (0.5 + sum_{q in P_c} sg)/denom
//
// R21: (1) prep scan/pack moved INTO mega (self-built in LDS from a 3KB mask
// buffer) -- kernel 1 is now pure GEMM + tiny mask block, removing the
// suspected serial prep pole. (2) F nodes 128 -> 64 (-9.4M sigE).

#define BB 384
#define CC 48
#define DD 512
#define MAXE 3072
#define NNODE 64
#define SCALE 144.269504089f  // 100 * log2(e)

__device__ __forceinline__ float sigE(float Eq, float Ep) {
    return Eq * __builtin_amdgcn_rcpf(Eq + Ep);
}

// ---- 1. sim tiles (blocks 0..143 = 36 tiles x 4 k-chunks) + masks (block 144)
__global__ __launch_bounds__(256) void simprep_kernel(
    const float* __restrict__ preds, const float* __restrict__ softlabels,
    float* __restrict__ simpart, float* __restrict__ wclass,
    uint2* __restrict__ maskbuf, float* __restrict__ out) {
    int tid = threadIdx.x;

    if (blockIdx.x < 144) {
        int t = blockIdx.x >> 2, kc = blockIdx.x & 3;
        int bi = t / 6, bj = t % 6;
        __shared__ __align__(16) float s_a[128][68];
        __shared__ __align__(16) float s_b[128][68];
        int kbase = kc * 128;
#pragma unroll
        for (int it = 0; it < 8; ++it) {
            int idx = it * 256 + tid;
            int r = idx >> 5;
            int c4 = idx & 31;
            float4 va = *reinterpret_cast<const float4*>(
                preds + (bi * 64 + r) * DD + kbase + c4 * 4);
            float4 vb = *reinterpret_cast<const float4*>(
                preds + (bj * 64 + r) * DD + kbase + c4 * 4);
            s_a[c4 * 4 + 0][r] = va.x; s_a[c4 * 4 + 1][r] = va.y;
            s_a[c4 * 4 + 2][r] = va.z; s_a[c4 * 4 + 3][r] = va.w;
            s_b[c4 * 4 + 0][r] = vb.x; s_b[c4 * 4 + 1][r] = vb.y;
            s_b[c4 * 4 + 2][r] = vb.z; s_b[c4 * 4 + 3][r] = vb.w;
        }
        __syncthreads();
        int ty = tid >> 4, tx = tid & 15;
        float4 acc0 = {0,0,0,0}, acc1 = {0,0,0,0}, acc2 = {0,0,0,0}, acc3 = {0,0,0,0};
#pragma unroll 4
        for (int k = 0; k < 128; ++k) {
            float4 a4 = *reinterpret_cast<const float4*>(&s_a[k][ty * 4]);
            float4 b4 = *reinterpret_cast<const float4*>(&s_b[k][tx * 4]);
            acc0.x += a4.x * b4.x; acc0.y += a4.x * b4.y; acc0.z += a4.x * b4.z; acc0.w += a4.x * b4.w;
            acc1.x += a4.y * b4.x; acc1.y += a4.y * b4.y; acc1.z += a4.y * b4.z; acc1.w += a4.y * b4.w;
            acc2.x += a4.z * b4.x; acc2.y += a4.z * b4.y; acc2.z += a4.z * b4.z; acc2.w += a4.z * b4.w;
            acc3.x += a4.w * b4.x; acc3.y += a4.w * b4.y; acc3.z += a4.w * b4.z; acc3.w += a4.w * b4.w;
        }
        if (blockIdx.x == 0 && tid == 0) out[0] = 1.0f;
        float* dst = simpart + kc * (BB * BB) + (bi * 64 + ty * 4) * BB + bj * 64 + tx * 4;
        *reinterpret_cast<float4*>(dst + 0 * BB) = acc0;
        *reinterpret_cast<float4*>(dst + 1 * BB) = acc1;
        *reinterpret_cast<float4*>(dst + 2 * BB) = acc2;
        *reinterpret_cast<float4*>(dst + 3 * BB) = acc3;
    } else {
        // ---- masks + class weights only (scan/pack now done in mega) ----
        __shared__ unsigned int s_mlo[BB];
        __shared__ unsigned int s_mhi[BB];
        int wave = tid >> 6, lane = tid & 63;

        for (int p = tid; p < BB; p += 256) {
            const float4* rowp = reinterpret_cast<const float4*>(softlabels + p * CC);
            unsigned int lo = 0, hi = 0;
#pragma unroll
            for (int v = 0; v < 12; ++v) {
                float4 x = rowp[v];
                unsigned int b = (x.x > 0.f ? 1u : 0u) | (x.y > 0.f ? 2u : 0u) |
                                 (x.z > 0.f ? 4u : 0u) | (x.w > 0.f ? 8u : 0u);
                if (v < 8) lo |= b << (4 * v);
                else       hi |= b << (4 * (v - 8));
            }
            s_mlo[p] = lo;
            s_mhi[p] = hi;
            maskbuf[p] = make_uint2(lo, hi);
        }
        __syncthreads();
        for (int c = wave; c < CC; c += 4) {
            int cnt = 0;
#pragma unroll
            for (int t = 0; t < BB / 64; ++t) {
                int p = t * 64 + lane;
                bool pos = ((c < 32 ? (s_mlo[p] >> c) : (s_mhi[p] >> (c - 32))) & 1u) != 0u;
                cnt += __popcll(__ballot(pos));
            }
            if (lane == 0) wclass[c] = (cnt >= 4) ? (1.0f / (float)cnt) : 0.0f;
        }
    }
}

// ---- 2. megaF: row/block; self-prep + in-block 64-node spline + exact phase B
__global__ __launch_bounds__(1024) void mega_kernel(
    const float* __restrict__ simpart, const float* __restrict__ softlabels,
    const float* __restrict__ wclass, const uint2* __restrict__ maskbuf,
    float* __restrict__ out) {
    int i = blockIdx.x;
    int tid = threadIdx.x;
    int wave = tid >> 6, lane = tid & 63;

    __shared__ float s_sk[BB];
    __shared__ __align__(16) float s_E[BB];
    __shared__ uint2 s_mq[BB];
    __shared__ int s_cnt[CC];
    __shared__ int s_soff[CC + 1];
    __shared__ float s_wsl[CC];
    __shared__ int s_fp[MAXE];
    __shared__ float s_Eq[MAXE];
    __shared__ float s_Fp[16][NNODE];
    __shared__ float s_F[NNODE];
    __shared__ float s_inv[BB];
    __shared__ float s_red[16];
    __shared__ float s_mx[16], s_mn[16], s_se[16];

    // phase 0: sim row -> sk, E; masks; wsl
    if (tid < BB) {
        int x = i * BB + tid;
        float sim = (simpart[x] + simpart[BB * BB + x]) +
                    (simpart[2 * BB * BB + x] + simpart[3 * BB * BB + x]);
        float sk = fminf(fmaxf(sim * SCALE, -45.0f), 45.0f);  // only self-sim clamps
        s_sk[tid] = sk;
        s_E[tid] = __builtin_amdgcn_exp2f(sk);
        s_mq[tid] = maskbuf[tid];
    }
    if (tid < CC) s_wsl[tid] = wclass[tid] * softlabels[i * CC + tid];
    __syncthreads();

    // self-prep: counts -> scan -> flat pack, all in LDS
    for (int c = wave; c < CC; c += 16) {
        int cnt = 0;
#pragma unroll
        for (int t = 0; t < BB / 64; ++t) {
            int p = t * 64 + lane;
            unsigned int mb = (c < 32) ? s_mq[p].x : s_mq[p].y;
            cnt += __popcll(__ballot(((mb >> (c & 31)) & 1u) != 0u));
        }
        if (lane == 0) s_cnt[c] = cnt;
    }
    __syncthreads();
    if (tid < 64) {
        int v = (tid < CC) ? s_cnt[tid] : 0;
#pragma unroll
        for (int d = 1; d < 64; d <<= 1) {
            int o = __shfl_up(v, d, 64);
            if (tid >= d) v += o;
        }
        if (tid < CC) s_soff[tid + 1] = v;
        if (tid == 0) s_soff[0] = 0;
    }
    __syncthreads();
    int nE = s_soff[CC];
    for (int c = wave; c < CC; c += 16) {
        int base = s_soff[c];
#pragma unroll
        for (int t = 0; t < BB / 64; ++t) {
            int p = t * 64 + lane;
            unsigned int mb = (c < 32) ? s_mq[p].x : s_mq[p].y;
            bool pos = ((mb >> (c & 31)) & 1u) != 0u;
            unsigned long long m = __ballot(pos);
            if (pos) s_fp[base + __popcll(m & ((1ull << lane) - 1ull))] = (c << 16) | p;
            base += __popcll(m);
        }
    }
    __syncthreads();

    // Eq staging + min/max/SE reductions
    for (int e = tid; e < nE; e += 1024) s_Eq[e] = s_E[s_fp[e] & 0xFFFF];
    float mx = -1e30f, mn = 1e30f, se = 0.f;
    if (tid < BB) {
        float v = s_sk[tid];
        mn = v;
        if (tid != i) { mx = v; se = s_E[tid]; }
    }
#pragma unroll
    for (int off = 32; off > 0; off >>= 1) {
        mx = fmaxf(mx, __shfl_xor(mx, off, 64));
        mn = fminf(mn, __shfl_xor(mn, off, 64));
        se += __shfl_xor(se, off, 64);
    }
    if (lane == 0) { s_mx[wave] = mx; s_mn[wave] = mn; s_se[wave] = se; }
    __syncthreads();
    mx = s_mx[0]; mn = s_mn[0]; se = s_se[0];
#pragma unroll
    for (int w = 1; w < 16; ++w) {
        mx = fmaxf(mx, s_mx[w]);
        mn = fminf(mn, s_mn[w]);
        se += s_se[w];
    }
    float lo = mn - 0.5f;
    float rng = fmaxf((mx + 0.5f) - lo, 1e-3f);
    float step = rng * (1.0f / (NNODE - 1));
    float invh = (NNODE - 1) / rng;

    // F at 64 nodes: lane = node, wave = q-chunk of 24; broadcast LDS reads
    {
        float En = __builtin_amdgcn_exp2f(lo + (float)lane * step);
        const float4* sv = reinterpret_cast<const float4*>(s_E + wave * 24);
        float a0 = 0.f, a1 = 0.f, a2 = 0.f;
#pragma unroll
        for (int t = 0; t < 6; t += 3) {
            float4 v0 = sv[t], v1 = sv[t + 1], v2 = sv[t + 2];
            a0 += sigE(v0.x, En) + sigE(v0.w, En);
            a1 += sigE(v0.y, En) + sigE(v1.x, En);
            a2 += sigE(v0.z, En) + sigE(v1.y, En);
            a0 += sigE(v1.z, En) + sigE(v2.y, En);
            a1 += sigE(v1.w, En) + sigE(v2.z, En);
            a2 += sigE(v2.x, En) + sigE(v2.w, En);
        }
        s_Fp[wave][lane] = (a0 + a1) + a2;
    }
    __syncthreads();
    if (tid < NNODE) {
        float f = 0.f;
#pragma unroll
        for (int c16 = 0; c16 < 16; ++c16) f += s_Fp[c16][tid];
        s_F[tid] = f;
    }
    __syncthreads();

    // denominators: cubic Lagrange; self-p exact tail
    if (tid < BB) {
        float d;
        if (tid == i) {
            d = 1.0f + se * 2.84217094e-14f;  // 2^-45 * SE
        } else {
            float t = (s_sk[tid] - lo) * invh;
            int j = (int)floorf(t);
            j = min(max(j, 1), NNODE - 3);
            float u = t - (float)j;
            float f0 = s_F[j - 1], f1 = s_F[j], f2 = s_F[j + 1], f3 = s_F[j + 2];
            float um1 = u + 1.f, u1 = u - 1.f, u2 = u - 2.f;
            float c0 = -u * u1 * u2 * (1.f / 6.f);
            float c1 = um1 * u1 * u2 * (1.f / 2.f);
            float c2 = -um1 * u * u2 * (1.f / 2.f);
            float c3 = um1 * u * u1 * (1.f / 6.f);
            d = 0.5f + (c0 * f0 + c1 * f1) + (c2 * f2 + c3 * f3);
        }
        s_inv[tid] = __builtin_amdgcn_rcpf(d);
    }
    __syncthreads();

    // phase B: exact, entry-parallel over full list
    float part = 0.f;
    for (int e = tid; e < nE; e += 1024) {
        int pk = s_fp[e];
        int c = pk >> 16, p = pk & 0xFFFF;
        int off = s_soff[c], m = s_soff[c + 1] - off;
        float Ep = s_E[p];
        float b0 = 0.f, b1 = 0.f, b2 = 0.f, b3 = 0.f;
        int j = 0;
        for (; j + 3 < m; j += 4) {
            b0 += sigE(s_Eq[off + j], Ep);
            b1 += sigE(s_Eq[off + j + 1], Ep);
            b2 += sigE(s_Eq[off + j + 2], Ep);
            b3 += sigE(s_Eq[off + j + 3], Ep);
        }
        for (; j < m; ++j) b0 += sigE(s_Eq[off + j], Ep);
        float s = (b0 + b1) + (b2 + b3);
        // s includes q==p (=0.5): numerator = 0.5 + s
        part += (0.5f + s) * s_inv[p] * s_wsl[c];
    }

    for (int off = 32; off > 0; off >>= 1) part += __shfl_down(part, off, 64);
    if (lane == 0) s_red[wave] = part;
    __syncthreads();
    if (tid == 0) {
        float tot = 0.f;
#pragma unroll
        for (int w = 0; w < 16; ++w) tot += s_red[w];
        atomicAdd(out, -tot * (1.0f / (float)BB));
    }
}

extern "C" void kernel_launch(void* const* d_in, const int* in_sizes, int n_in,
                              void* d_out, int out_size, void* d_ws, size_t ws_size,
                              hipStream_t stream) {
    const float* preds = (const float*)d_in[0];       // (384,512) f32
    const float* softlabels = (const float*)d_in[1];  // (384,48) f32
    float* out = (float*)d_out;

    char* ws = (char*)d_ws;
    float* simpart = (float*)(ws + 0);        // 2359296
    float* wclass  = (float*)(ws + 2359296);  // 192
    uint2* maskbuf = (uint2*)(ws + 2359488);  // 3072

    simprep_kernel<<<145, 256, 0, stream>>>(preds, softlabels, simpart, wclass,
                                            maskbuf, out);
    mega_kernel<<<BB, 1024, 0, stream>>>(simpart, softlabels, wclass, maskbuf, out);
}